// Round 8
// baseline (199.240 us; speedup 1.0000x reference)
//
#include <hip/hip_runtime.h>
#include <math.h>

#define B_   8
#define C_   256
#define H_   64
#define W_   64
#define O_   256
#define KK_  9
#define CK_  2304      // C_*KK_
#define HW_  4096      // H_*W_
#define BN_EPS 1e-5f

typedef __bf16 bf16x8 __attribute__((ext_vector_type(8)));
typedef float  f32x4  __attribute__((ext_vector_type(4)));

static __device__ __forceinline__ unsigned short f2bf(float f) {   // RNE (weights)
    unsigned int u = __float_as_uint(f);
    unsigned int r = (u + 0x7fffu + ((u >> 16) & 1u)) >> 16;
    return (unsigned short)r;
}
// pack two f32 -> bf16x2 with round-half-up (2 adds + 1 v_perm)
static __device__ __forceinline__ unsigned int packbf2(float lo, float hi) {
    unsigned int ul = __float_as_uint(lo) + 0x8000u;
    unsigned int uh = __float_as_uint(hi) + 0x8000u;
    return __builtin_amdgcn_perm(uh, ul, 0x07060302u);
}
static __device__ __forceinline__ float bflo(unsigned int u) {
    return __uint_as_float(u << 16);
}
static __device__ __forceinline__ float bfhi(unsigned int u) {
    return __uint_as_float(u & 0xffff0000u);
}

// ---- kernel 0: prep. 656 blocks x 256 thr. (R7 version, XCD-matched swizzle)
__global__ __launch_bounds__(256) void prep_kernel(
    const float* __restrict__ x, const float* __restrict__ w,
    const float* __restrict__ w_off,
    unsigned short* __restrict__ xT, unsigned short* __restrict__ wKf,
    unsigned short* __restrict__ wof)
{
    __shared__ float tile[64][65];     // transpose staging
    __shared__ float wbuf[4608];       // weight staging (16 o x 288)

    const int blk = blockIdx.x;
    const int tid = threadIdx.x, lane = tid & 63, tg = tid >> 6;

    if (blk < 512) {
        // XCD-contiguous h-chunks: XCD x gets h in [8x, 8x+8), all b.
        const int L = (blk & 7) * 64 + (blk >> 3);
        const int b = L & 7, h = L >> 3;
        const int hwb = h * W_;
#pragma unroll
        for (int ct = 0; ct < 4; ++ct) {
            const int c0 = ct * 64;
#pragma unroll
            for (int r = 0; r < 16; ++r) {
                int c_l = tg + r * 4;
                tile[c_l][lane] = x[((size_t)(b * C_ + c0 + c_l)) * HW_ + hwb + lane];
            }
            __syncthreads();
#pragma unroll
            for (int it = 0; it < 4; ++it) {
                const int hw_l = tg * 16 + it * 4 + (lane >> 4);
                const int c_l4 = (lane & 15) * 4;
                float v0 = tile[c_l4 + 0][hw_l];
                float v1 = tile[c_l4 + 1][hw_l];
                float v2 = tile[c_l4 + 2][hw_l];
                float v3 = tile[c_l4 + 3][hw_l];
                uint2 pk;
                pk.x = packbf2(v0, v1);
                pk.y = packbf2(v2, v3);
                *(uint2*)&xT[((size_t)(b * HW_ + hwb + hw_l)) * C_ + c0 + c_l4] = pk;
            }
            __syncthreads();
        }
    } else if (blk < 640) {
        const int t2 = blk - 512;
        const int NT = t2 >> 3, cb = t2 & 7;
#pragma unroll
        for (int i = 0; i < 18; ++i) {
            int j = i * 256 + tid;
            int o_l = j / 288, rest = j - o_l * 288;
            wbuf[o_l * 288 + rest] = w[(size_t)(NT * 16 + o_l) * CK_ + cb * 288 + rest];
        }
        __syncthreads();
#pragma unroll
        for (int i = 0; i < 18; ++i) {
            int d = i * 256 + tid;
            int tap = d >> 9, r5 = d & 511;
            int ln = r5 >> 3, e = r5 & 7;
            int n16 = ln & 15, q = ln >> 4;
            float val = wbuf[n16 * 288 + (q * 8 + e) * 9 + tap];
            wKf[((size_t)(NT * 72 + tap * 8 + cb) * 64 + ln) * 8 + e] = f2bf(val);
        }
    } else {
        const int t2 = blk - 640;
        const int NT = t2 >> 3, cb = t2 & 7;
#pragma unroll
        for (int i = 0; i < 18; ++i) {
            int j = i * 256 + tid;
            int o_l = j / 288, rest = j - o_l * 288;
            int o = NT * 16 + o_l;
            wbuf[o_l * 288 + rest] =
                (o < 27) ? w_off[(size_t)o * CK_ + cb * 288 + rest] : 0.f;
        }
        __syncthreads();
#pragma unroll
        for (int i = 0; i < 18; ++i) {
            int d = i * 256 + tid;
            int tap = d >> 9, r5 = d & 511;
            int ln = r5 >> 3, e = r5 & 7;
            int n16 = ln & 15, q = ln >> 4;
            float val = wbuf[n16 * 288 + (q * 8 + e) * 9 + tap];
            wof[((size_t)(NT * 72 + tap * 8 + cb) * 64 + ln) * 8 + e] = f2bf(val);
        }
    }
}

// ---- kernel 1: fused offset-conv (MFMA) + sample + MFMA GEMM + BN + ReLU
// v8: VMEM-BYTES restructure. Block = 2 output rows (128 px) x 256 O,
//     grid 256 (1 block/CU), 512 thr / 8 waves, wave = 128 px x 32 O
//     (acc[8][2]). Same per-wave wKf B-frags now serve 2x the M-work ->
//     B-stream halves (590->295 MB). Phase A: both rows from 4 staged
//     input rows; per-tap-row wof frags kept in regs across adjacent
//     stages -> wof halves (295->147 MB). Total VMEM 1.56->1.10 GB.
__global__ __launch_bounds__(512, 2) void dcn_fused_kernel(
    const unsigned short* __restrict__ xT, const unsigned short* __restrict__ wKf,
    const unsigned short* __restrict__ wof, const float* __restrict__ b_off,
    const float* __restrict__ bias, const float* __restrict__ gamma,
    const float* __restrict__ beta, const float* __restrict__ rmean,
    const float* __restrict__ rvar, float* __restrict__ out)
{
    // layout: wgtv float4[1152]  @ 0      (18432 B)
    //         idxv ushort4[1152] @ 18432  (9216 B, ends 27648)
    //         Abuf [8][8][64][8] bf16 @ 34848 (65536 B, ends 100384)
    // overlays: rowbuf [66][264] bf16 @ 0 (34848 B; dead before tables)
    //           omb [27][128] f32 @ 34848 (dead before first Abuf write)
    __shared__ __align__(16) unsigned char smem[100384];
    unsigned short* rowbuf = (unsigned short*)smem;
    float4*  wgtv = (float4*)smem;
    ushort4* idxv = (ushort4*)(smem + 18432);
    typedef float OmbT[27][128];
    OmbT& omb = *(OmbT*)(smem + 34848);
    typedef unsigned short AbufT[8][8][64][8];   // [cc][mi][row][e]
    AbufT& Abuf = *(AbufT*)(smem + 34848);

    // XCD-contiguous: 256 = 8 XCD x 32; XCD x gets h-pairs covering h in [8x,8x+8)
    const int pblk = blockIdx.x;
    const int L = (pblk & 7) * 32 + (pblk >> 3);
    const int b = L & 7, hp = L >> 3;
    const int h = hp * 2;                        // block covers rows h, h+1
    const int tid = threadIdx.x, lane = tid & 63, wv = tid >> 6;
    const int m16 = lane & 15, q = lane >> 4;

    // ================= Phase A: offset conv, 2 output rows =================
    if (tid < 33) {                                  // zero halo px=-1 (row 0)
        *(uint4*)&rowbuf[tid * 8] = make_uint4(0u, 0u, 0u, 0u);
    } else if (tid >= 256 && tid < 289) {            // zero halo px=64 (row 65)
        *(uint4*)&rowbuf[65 * 264 + (tid - 256) * 8] = make_uint4(0u, 0u, 0u, 0u);
    }

    const int mi_a = wv & 3, nj_a = wv >> 2;
    f32x4 oacc0 = {0.f, 0.f, 0.f, 0.f};             // output row h
    f32x4 oacc1 = {0.f, 0.f, 0.f, 0.f};             // output row h+1
    const uint4* wof4 = (const uint4*)wof;
    uint4 bsv[24];                                   // tap-row B frags (3s x 8cc)

#pragma unroll
    for (int st = 0; st < 4; ++st) {                 // input rows h-1 .. h+2
        const int hh = h - 1 + st;
        const bool vr = (hh >= 0) && (hh < H_);      // block-uniform
        __syncthreads();                             // prior stage reads done
        if (vr) {
            const uint4* src = (const uint4*)&xT[((size_t)(b * HW_ + hh * W_)) * C_];
#pragma unroll
            for (int i = 0; i < 4; ++i) {
                const int idx8 = i * 512 + tid;      // 2048 chunks of 8 ch (16 B)
                uint4 v = src[idx8];
                const int px = idx8 >> 5, c8 = (idx8 & 31) * 8;
                *(uint4*)&rowbuf[(px + 1) * 264 + c8] = v;
            }
        }
        __syncthreads();
#pragma unroll
        for (int s = 0; s < 3; ++s) {
            const unsigned short* arow = &rowbuf[(mi_a * 16 + m16 + s) * 264 + q * 8];
#pragma unroll
            for (int cc = 0; cc < 8; ++cc) {
                bf16x8 a;
                if (vr) a = *(const bf16x8*)&arow[cc * 32];
                // output row h+1: tap-row st-1, B loaded LAST stage (reuse)
                if (st >= 1 && vr)
                    oacc1 = __builtin_amdgcn_mfma_f32_16x16x32_bf16(
                        a, __builtin_bit_cast(bf16x8, bsv[s * 8 + cc]), oacc1, 0, 0, 0);
                // output row h: tap-row st; load B (unconditionally — weights
                // always valid; needed by next stage's oacc1 even if !vr)
                if (st <= 2) {
                    bsv[s * 8 + cc] =
                        wof4[(size_t)(nj_a * 72 + (st * 3 + s) * 8 + cc) * 64 + lane];
                    if (vr)
                        oacc0 = __builtin_amdgcn_mfma_f32_16x16x32_bf16(
                            a, __builtin_bit_cast(bf16x8, bsv[s * 8 + cc]), oacc0, 0, 0, 0);
                }
            }
        }
    }
    __syncthreads();                      // ALL rowbuf reads done (omb overlays Abuf)

    // phase-A epilogue: bias + sigmoid(mod) -> omb[t][p]  (p = o*64 + px)
    {
        const int t = nj_a * 16 + m16;
        if (t < 27) {
            const float bo = b_off[t];
#pragma unroll
            for (int o = 0; o < 2; ++o) {
                f32x4 v = o ? oacc1 : oacc0;
                float s0 = v[0] + bo, s1 = v[1] + bo, s2 = v[2] + bo, s3 = v[3] + bo;
                if (t >= 18) {
                    s0 = 1.f / (1.f + expf(-s0));
                    s1 = 1.f / (1.f + expf(-s1));
                    s2 = 1.f / (1.f + expf(-s2));
                    s3 = 1.f / (1.f + expf(-s3));
                }
                float4 rr; rr.x = s0; rr.y = s1; rr.z = s2; rr.w = s3;
                *(float4*)&omb[t][o * 64 + mi_a * 16 + q * 4] = rr;
            }
        }
    }
    __syncthreads();                      // omb visible

    // ---- per-(pixel,tap) tables: 1152 entries (overwrite rowbuf region) ----
    for (int i = tid; i < 1152; i += 512) {
        int p = i / 9, t = i - p * 9;
        int o = p >> 6, px_i = p & 63;
        float dy = omb[t][p];
        float dx = omb[t + 9][p];
        float md = omb[t + 18][p];
        float py = (float)(h + o - 1 + t / 3) + dy;
        float px = (float)(px_i - 1 + t % 3) + dx;
        float y0f = floorf(py), x0f = floorf(px);
        int   y0 = (int)y0f,    x0 = (int)x0f;
        float fy = py - y0f,    fx = px - x0f;
        int y0c = min(max(y0,     0), H_ - 1), y1c = min(max(y0 + 1, 0), H_ - 1);
        int x0c = min(max(x0,     0), W_ - 1), x1c = min(max(x0 + 1, 0), W_ - 1);
        float vy0 = (y0     >= 0 && y0     < H_) ? 1.f : 0.f;
        float vy1 = (y0 + 1 >= 0 && y0 + 1 < H_) ? 1.f : 0.f;
        float vx0 = (x0     >= 0 && x0     < W_) ? 1.f : 0.f;
        float vx1 = (x0 + 1 >= 0 && x0 + 1 < W_) ? 1.f : 0.f;
        wgtv[i] = make_float4((1.f - fy) * (1.f - fx) * vy0 * vx0 * md,
                              (1.f - fy) * fx         * vy0 * vx1 * md,
                              fy         * (1.f - fx) * vy1 * vx0 * md,
                              fy         * fx         * vy1 * vx1 * md);
        ushort4 uu;
        uu.x = (unsigned short)(y0c * W_ + x0c);
        uu.y = (unsigned short)(y0c * W_ + x1c);
        uu.z = (unsigned short)(y1c * W_ + x0c);
        uu.w = (unsigned short)(y1c * W_ + x1c);
        idxv[i] = uu;
    }
    __syncthreads();                      // tables visible; omb dead

    // ================= Phase B: sample + GEMM =================
    f32x4 acc[8][2];
#pragma unroll
    for (int mi = 0; mi < 8; ++mi)
#pragma unroll
        for (int nj = 0; nj < 2; ++nj)
#pragma unroll
            for (int r = 0; r < 4; ++r) acc[mi][nj][r] = 0.f;

    const uint4* wKf4 = (const uint4*)wKf;
    const char* xTbL = (const char*)xT + (size_t)(b * HW_) * (C_ * 2) + lane * 8;

    // sampling write-dest precompute (lane covers channels 4*lane .. 4*lane+3)
    const int s_cc = lane >> 3;                   // 32-ch chunk
    const int s_q2 = (lane >> 1) & 3;             // k-quad within chunk
    const int s_j0 = (lane & 1) * 4;              // element offset within frag row
    const int s_xr = (s_q2 << 1) ^ s_cc;          // XOR swizzle for bank spread
    // wave wv samples px P = wv*16 + pp  (= m-tile wv, within-tile index pp)

    const int r_row = lane ^ ((lane >> 4) << 1);  // MFMA-side read row (pre-XOR by cc)

    // B-pipeline registers: bA/bB each hold one cc-pair batch {2cc x 2nj}
    uint4 bA[4], bB[4];
    auto loadB = [&](uint4* dst, int t_, int p_) {
#pragma unroll
        for (int c2 = 0; c2 < 2; ++c2)
#pragma unroll
            for (int nj = 0; nj < 2; ++nj)
                dst[c2 * 2 + nj] =
                    wKf4[(size_t)((wv * 2 + nj) * 72 + t_ * 8 + p_ * 2 + c2) * 64 + lane];
    };
    auto mfmaPair = [&](int p_, const uint4* Bf) {
#pragma unroll
        for (int c2 = 0; c2 < 2; ++c2) {
            const int cc = p_ * 2 + c2;
            const int rr = r_row ^ cc;
            bf16x8 a[8];
#pragma unroll
            for (int mi = 0; mi < 8; ++mi)
                a[mi] = *(const bf16x8*)&Abuf[cc][mi][rr][0];
#pragma unroll
            for (int nj = 0; nj < 2; ++nj) {
                bf16x8 bb = __builtin_bit_cast(bf16x8, Bf[c2 * 2 + nj]);
#pragma unroll
                for (int mi = 0; mi < 8; ++mi)
                    acc[mi][nj] = __builtin_amdgcn_mfma_f32_16x16x32_bf16(
                        a[mi], bb, acc[mi][nj], 0, 0, 0);
            }
        }
    };

    loadB(bA, 0, 0);                      // preload tap0 cc{0,1}

#pragma unroll 1
    for (int tap = 0; tap < 9; ++tap) {
        // ---- sample 16 pixels: coalesced 512-B corner loads, weighted sum ----
        uint2 pk[16];
#pragma unroll
        for (int pp = 0; pp < 16; ++pp) {
            const int p = wv * 16 + pp;
            const ushort4 iq = idxv[p * 9 + tap];
            const float4  wq = wgtv[p * 9 + tap];
            const uint2 k0 = *(const uint2*)(xTbL + ((int)iq.x << 9));
            const uint2 k1 = *(const uint2*)(xTbL + ((int)iq.y << 9));
            const uint2 k2 = *(const uint2*)(xTbL + ((int)iq.z << 9));
            const uint2 k3 = *(const uint2*)(xTbL + ((int)iq.w << 9));
            float g0 = wq.x*bflo(k0.x) + wq.y*bflo(k1.x) + wq.z*bflo(k2.x) + wq.w*bflo(k3.x);
            float g1 = wq.x*bfhi(k0.x) + wq.y*bfhi(k1.x) + wq.z*bfhi(k2.x) + wq.w*bfhi(k3.x);
            float g2 = wq.x*bflo(k0.y) + wq.y*bflo(k1.y) + wq.z*bflo(k2.y) + wq.w*bflo(k3.y);
            float g3 = wq.x*bfhi(k0.y) + wq.y*bfhi(k1.y) + wq.z*bfhi(k2.y) + wq.w*bfhi(k3.y);
            pk[pp].x = packbf2(g0, g1);
            pk[pp].y = packbf2(g2, g3);
        }

        __syncthreads();                  // previous tap's A-frag reads complete
#pragma unroll
        for (int pp = 0; pp < 16; ++pp) {
            const int row = (pp ^ s_xr) | (s_q2 << 4);     // swizzled frag row
            *(uint2*)&Abuf[s_cc][wv][row][s_j0] = pk[pp];
        }
        __syncthreads();                  // tap's A tile visible

        // ---- MFMA: 8 K-steps, B-frags pipelined one cc-pair ahead ----
        __builtin_amdgcn_s_setprio(1);
        loadB(bB, tap, 1);                // cc2,3 in flight under MFMA(cc0,1)
        mfmaPair(0, bA);
        loadB(bA, tap, 2);                // cc4,5
        mfmaPair(1, bB);
        loadB(bB, tap, 3);                // cc6,7
        mfmaPair(2, bA);
        if (tap < 8) loadB(bA, tap + 1, 0);
        mfmaPair(3, bB);
        __builtin_amdgcn_s_setprio(0);
    }

    // ---- epilogue: conv bias + BN + ReLU, nontemporal float4 stores ----
#pragma unroll
    for (int nj = 0; nj < 2; ++nj) {
        const int o = wv * 32 + nj * 16 + m16;
        const float inv = gamma[o] * rsqrtf(rvar[o] + BN_EPS);
        const float sh  = beta[o] + (bias[o] - rmean[o]) * inv;
        float* ob = out + ((size_t)(b * O_ + o)) * HW_ + h * W_;
#pragma unroll
        for (int mi = 0; mi < 8; ++mi) {
            // global px = mi*16 + q*4 + j  ->  row mi>>2, x (mi&3)*16 + q*4
            f32x4 v = acc[mi][nj];
            f32x4 r;
            r[0] = fmaxf(v[0] * inv + sh, 0.f);
            r[1] = fmaxf(v[1] * inv + sh, 0.f);
            r[2] = fmaxf(v[2] * inv + sh, 0.f);
            r[3] = fmaxf(v[3] * inv + sh, 0.f);
            __builtin_nontemporal_store(
                r, (f32x4*)&ob[(mi >> 2) * W_ + (mi & 3) * 16 + q * 4]);
        }
    }
}

extern "C" void kernel_launch(void* const* d_in, const int* in_sizes, int n_in,
                              void* d_out, int out_size, void* d_ws, size_t ws_size,
                              hipStream_t stream) {
    const float* x     = (const float*)d_in[0];
    const float* w_off = (const float*)d_in[1];
    const float* b_off = (const float*)d_in[2];
    const float* w     = (const float*)d_in[3];
    const float* bias  = (const float*)d_in[4];
    const float* gamma = (const float*)d_in[5];
    const float* beta  = (const float*)d_in[6];
    const float* rmean = (const float*)d_in[7];
    const float* rvar  = (const float*)d_in[8];
    float* out = (float*)d_out;

    unsigned short* xT  = (unsigned short*)d_ws;              // 8388608 bf16 (16 MB)
    unsigned short* wKf = xT + 8388608;                       // 589824 bf16
    unsigned short* wof = wKf + 589824;                       // 73728 bf16

    prep_kernel<<<656, 256, 0, stream>>>(x, w, w_off, xT, wKf, wof);
    dcn_fused_kernel<<<256, 512, 0, stream>>>(
        xT, wKf, wof, b_off, bias, gamma, beta, rmean, rvar, out);
}

// Round 9
// 179.374 us; speedup vs baseline: 1.1108x; 1.1108x over previous
//
#include <hip/hip_runtime.h>
#include <math.h>

#define B_   8
#define C_   256
#define H_   64
#define W_   64
#define O_   256
#define KK_  9
#define CK_  2304      // C_*KK_
#define HW_  4096      // H_*W_
#define BN_EPS 1e-5f

typedef __bf16 bf16x8 __attribute__((ext_vector_type(8)));
typedef float  f32x4  __attribute__((ext_vector_type(4)));

static __device__ __forceinline__ unsigned short f2bf(float f) {   // RNE (weights)
    unsigned int u = __float_as_uint(f);
    unsigned int r = (u + 0x7fffu + ((u >> 16) & 1u)) >> 16;
    return (unsigned short)r;
}
// pack two f32 -> bf16x2 with round-half-up (2 adds + 1 v_perm)
static __device__ __forceinline__ unsigned int packbf2(float lo, float hi) {
    unsigned int ul = __float_as_uint(lo) + 0x8000u;
    unsigned int uh = __float_as_uint(hi) + 0x8000u;
    return __builtin_amdgcn_perm(uh, ul, 0x07060302u);
}
static __device__ __forceinline__ float bflo(unsigned int u) {
    return __uint_as_float(u << 16);
}
static __device__ __forceinline__ float bfhi(unsigned int u) {
    return __uint_as_float(u & 0xffff0000u);
}

// ---- kernel 0: prep. 656 blocks x 256 thr. (R7 version, XCD-matched swizzle)
__global__ __launch_bounds__(256) void prep_kernel(
    const float* __restrict__ x, const float* __restrict__ w,
    const float* __restrict__ w_off,
    unsigned short* __restrict__ xT, unsigned short* __restrict__ wKf,
    unsigned short* __restrict__ wof)
{
    __shared__ float tile[64][65];     // transpose staging
    __shared__ float wbuf[4608];       // weight staging (16 o x 288)

    const int blk = blockIdx.x;
    const int tid = threadIdx.x, lane = tid & 63, tg = tid >> 6;

    if (blk < 512) {
        // XCD-contiguous h-chunks: XCD x gets h in [8x, 8x+8), all b.
        const int L = (blk & 7) * 64 + (blk >> 3);
        const int b = L & 7, h = L >> 3;
        const int hwb = h * W_;
#pragma unroll
        for (int ct = 0; ct < 4; ++ct) {
            const int c0 = ct * 64;
#pragma unroll
            for (int r = 0; r < 16; ++r) {
                int c_l = tg + r * 4;
                tile[c_l][lane] = x[((size_t)(b * C_ + c0 + c_l)) * HW_ + hwb + lane];
            }
            __syncthreads();
#pragma unroll
            for (int it = 0; it < 4; ++it) {
                const int hw_l = tg * 16 + it * 4 + (lane >> 4);
                const int c_l4 = (lane & 15) * 4;
                float v0 = tile[c_l4 + 0][hw_l];
                float v1 = tile[c_l4 + 1][hw_l];
                float v2 = tile[c_l4 + 2][hw_l];
                float v3 = tile[c_l4 + 3][hw_l];
                uint2 pk;
                pk.x = packbf2(v0, v1);
                pk.y = packbf2(v2, v3);
                *(uint2*)&xT[((size_t)(b * HW_ + hwb + hw_l)) * C_ + c0 + c_l4] = pk;
            }
            __syncthreads();
        }
    } else if (blk < 640) {
        const int t2 = blk - 512;
        const int NT = t2 >> 3, cb = t2 & 7;
#pragma unroll
        for (int i = 0; i < 18; ++i) {
            int j = i * 256 + tid;
            int o_l = j / 288, rest = j - o_l * 288;
            wbuf[o_l * 288 + rest] = w[(size_t)(NT * 16 + o_l) * CK_ + cb * 288 + rest];
        }
        __syncthreads();
#pragma unroll
        for (int i = 0; i < 18; ++i) {
            int d = i * 256 + tid;
            int tap = d >> 9, r5 = d & 511;
            int ln = r5 >> 3, e = r5 & 7;
            int n16 = ln & 15, q = ln >> 4;
            float val = wbuf[n16 * 288 + (q * 8 + e) * 9 + tap];
            wKf[((size_t)(NT * 72 + tap * 8 + cb) * 64 + ln) * 8 + e] = f2bf(val);
        }
    } else {
        const int t2 = blk - 640;
        const int NT = t2 >> 3, cb = t2 & 7;
#pragma unroll
        for (int i = 0; i < 18; ++i) {
            int j = i * 256 + tid;
            int o_l = j / 288, rest = j - o_l * 288;
            int o = NT * 16 + o_l;
            wbuf[o_l * 288 + rest] =
                (o < 27) ? w_off[(size_t)o * CK_ + cb * 288 + rest] : 0.f;
        }
        __syncthreads();
#pragma unroll
        for (int i = 0; i < 18; ++i) {
            int d = i * 256 + tid;
            int tap = d >> 9, r5 = d & 511;
            int ln = r5 >> 3, e = r5 & 7;
            int n16 = ln & 15, q = ln >> 4;
            float val = wbuf[n16 * 288 + (q * 8 + e) * 9 + tap];
            wof[((size_t)(NT * 72 + tap * 8 + cb) * 64 + ln) * 8 + e] = f2bf(val);
        }
    }
}

// ---- kernel 1: fused offset-conv (MFMA) + sample + MFMA GEMM + BN + ReLU
// 512 blocks / 512 thr / 8 waves. v9 = v7 + DEEP GATHER HOIST:
//   all 32 corner loads (64 VGPR) issue before any wsum -> one exposed L2
//   round-trip per tap instead of ~4-8. Paid for by dropping the bA/bB
//   register pipeline (v6 proved JIT B-loads are neutral). Single-variable
//   experiment vs v7.
__global__ __launch_bounds__(512, 4) void dcn_fused_kernel(
    const unsigned short* __restrict__ xT, const unsigned short* __restrict__ wKf,
    const unsigned short* __restrict__ wof, const float* __restrict__ b_off,
    const float* __restrict__ bias, const float* __restrict__ gamma,
    const float* __restrict__ beta, const float* __restrict__ rmean,
    const float* __restrict__ rvar, float* __restrict__ out)
{
    // region 0 (0..34847):      rowbuf [66][264] bf16 (phase A), then
    //                           wgtv[576] float4 (0..9215) + idxv[576] int4 (9216..18431)
    // region 1 (34848..41759):  omb [27][64] f32
    // region 2 (41760..74527):  Abuf [8][4][64][8] bf16
    __shared__ __align__(16) unsigned char smem[74528];
    unsigned short* rowbuf = (unsigned short*)smem;
    float4*         wgtv   = (float4*)smem;
    int4*           idxv   = (int4*)(smem + 9216);
    typedef float OmbT[27][64];
    OmbT& omb = *(OmbT*)(smem + 34848);
    typedef unsigned short AbufT[8][4][64][8];
    AbufT& Abuf = *(AbufT*)(smem + 41760);

    // XCD-contiguous h-chunks (bijective: 512 = 8 XCD x 64)
    const int pblk = blockIdx.x;
    const int L = (pblk & 7) * 64 + (pblk >> 3);
    const int b = L & 7, h = L >> 3;
    const int tid = threadIdx.x, lane = tid & 63, wv = tid >> 6;
    const int m16 = lane & 15, q = lane >> 4;

    // ================= Phase A: offset conv =================
    if (tid < 33) {                                  // zero halo px=-1 (row 0)
        *(uint4*)&rowbuf[tid * 8] = make_uint4(0u, 0u, 0u, 0u);
    } else if (tid >= 256 && tid < 289) {            // zero halo px=64 (row 65)
        *(uint4*)&rowbuf[65 * 264 + (tid - 256) * 8] = make_uint4(0u, 0u, 0u, 0u);
    }

    const int mi_a = wv & 3, nj_a = wv >> 2;
    f32x4 oacc = {0.f, 0.f, 0.f, 0.f};
    const uint4* wof4 = (const uint4*)wof;

    for (int r = 0; r < 3; ++r) {
        const int hh = h - 1 + r;
        const bool vr = (hh >= 0) && (hh < H_);      // block-uniform
        __syncthreads();                             // prior r reads done / halos visible
        if (vr) {
            const uint4* src = (const uint4*)&xT[((size_t)(b * HW_ + hh * W_)) * C_];
#pragma unroll
            for (int i = 0; i < 4; ++i) {
                const int idx8 = i * 512 + tid;      // 2048 chunks of 8 ch (16 B)
                uint4 v = src[idx8];
                const int px = idx8 >> 5, c8 = (idx8 & 31) * 8;
                *(uint4*)&rowbuf[(px + 1) * 264 + c8] = v;
            }
        }
        __syncthreads();
        if (vr) {
#pragma unroll
            for (int s = 0; s < 3; ++s) {
                const unsigned short* arow = &rowbuf[(mi_a * 16 + m16 + s) * 264 + q * 8];
#pragma unroll
                for (int cc = 0; cc < 8; ++cc) {
                    bf16x8 a = *(const bf16x8*)&arow[cc * 32];
                    uint4 braw = wof4[(size_t)(nj_a * 72 + (r * 3 + s) * 8 + cc) * 64 + lane];
                    oacc = __builtin_amdgcn_mfma_f32_16x16x32_bf16(
                        a, __builtin_bit_cast(bf16x8, braw), oacc, 0, 0, 0);
                }
            }
        }
    }
    // phase-A epilogue: bias + sigmoid(mod) -> omb[t][px]
    {
        const int t = nj_a * 16 + m16;
        if (t < 27) {
            const float bo = b_off[t];
            float s0 = oacc[0] + bo, s1 = oacc[1] + bo,
                  s2 = oacc[2] + bo, s3 = oacc[3] + bo;
            if (t >= 18) {
                s0 = 1.f / (1.f + expf(-s0));
                s1 = 1.f / (1.f + expf(-s1));
                s2 = 1.f / (1.f + expf(-s2));
                s3 = 1.f / (1.f + expf(-s3));
            }
            float4 rr; rr.x = s0; rr.y = s1; rr.z = s2; rr.w = s3;
            *(float4*)&omb[t][mi_a * 16 + q * 4] = rr;
        }
    }
    __syncthreads();                      // omb visible; rowbuf dead

    // ---- per-(pixel,tap) tables (overwrite rowbuf region) ----
    for (int i = tid; i < 576; i += 512) {
        int p = i / 9, t = i - p * 9;
        float dy = omb[t][p];
        float dx = omb[t + 9][p];
        float md = omb[t + 18][p];
        float py = (float)(h - 1 + t / 3) + dy;
        float px = (float)(p - 1 + t % 3) + dx;
        float y0f = floorf(py), x0f = floorf(px);
        int   y0 = (int)y0f,    x0 = (int)x0f;
        float fy = py - y0f,    fx = px - x0f;
        int y0c = min(max(y0,     0), H_ - 1), y1c = min(max(y0 + 1, 0), H_ - 1);
        int x0c = min(max(x0,     0), W_ - 1), x1c = min(max(x0 + 1, 0), W_ - 1);
        float vy0 = (y0     >= 0 && y0     < H_) ? 1.f : 0.f;
        float vy1 = (y0 + 1 >= 0 && y0 + 1 < H_) ? 1.f : 0.f;
        float vx0 = (x0     >= 0 && x0     < W_) ? 1.f : 0.f;
        float vx1 = (x0 + 1 >= 0 && x0 + 1 < W_) ? 1.f : 0.f;
        wgtv[i] = make_float4((1.f - fy) * (1.f - fx) * vy0 * vx0 * md,
                              (1.f - fy) * fx         * vy0 * vx1 * md,
                              fy         * (1.f - fx) * vy1 * vx0 * md,
                              fy         * fx         * vy1 * vx1 * md);
        const int rowb = (b * HW_) * (C_ * 2);       // byte offset of batch b in xT
        idxv[i] = make_int4(rowb + (y0c * W_ + x0c) * (C_ * 2),
                            rowb + (y0c * W_ + x1c) * (C_ * 2),
                            rowb + (y1c * W_ + x0c) * (C_ * 2),
                            rowb + (y1c * W_ + x1c) * (C_ * 2));
    }
    __syncthreads();

    // ================= Phase B: sample + GEMM =================
    f32x4 acc[4][2];
#pragma unroll
    for (int mi = 0; mi < 4; ++mi)
#pragma unroll
        for (int nj = 0; nj < 2; ++nj)
#pragma unroll
            for (int r = 0; r < 4; ++r) acc[mi][nj][r] = 0.f;

    const uint4* wKf4 = (const uint4*)wKf;
    const char*  xTb  = (const char*)xT;

    // sampling write-dest precompute (lane covers channels 4*lane .. 4*lane+3)
    const int s_cc = lane >> 3;                   // 32-ch chunk
    const int s_q2 = (lane >> 1) & 3;             // k-quad within chunk
    const int s_j0 = (lane & 1) * 4;              // element offset within frag row
    const int s_xr = (s_q2 << 1) ^ s_cc;          // XOR swizzle for bank spread
    const int s_mi = wv >> 1;                     // m-tile this wave's pixels fall in
    const int s_pb = (wv & 1) * 8;                // pixel base within m-tile
    const int loff = lane * 8;                    // byte offset within 512-B pixel row

    const int r_row = lane ^ ((lane >> 4) << 1);  // MFMA-side read row (pre-XOR by cc)

#pragma unroll 1
    for (int tap = 0; tap < 9; ++tap) {
        // ---- DEEP HOIST: issue ALL 32 corner loads before any wsum ----
        uint2 kr[8][4];                   // 64 VGPR in flight
#pragma unroll
        for (int pp = 0; pp < 8; ++pp) {
            const int4 iq = idxv[(wv * 8 + pp) * 9 + tap];
            kr[pp][0] = *(const uint2*)(xTb + iq.x + loff);
            kr[pp][1] = *(const uint2*)(xTb + iq.y + loff);
            kr[pp][2] = *(const uint2*)(xTb + iq.z + loff);
            kr[pp][3] = *(const uint2*)(xTb + iq.w + loff);
        }
        // ---- weighted sums (single exposed wait on the oldest loads) ----
        uint2 pk[8];
#pragma unroll
        for (int pp = 0; pp < 8; ++pp) {
            const float4 wq = wgtv[(wv * 8 + pp) * 9 + tap];
            float g0 = wq.x*bflo(kr[pp][0].x) + wq.y*bflo(kr[pp][1].x)
                     + wq.z*bflo(kr[pp][2].x) + wq.w*bflo(kr[pp][3].x);
            float g1 = wq.x*bfhi(kr[pp][0].x) + wq.y*bfhi(kr[pp][1].x)
                     + wq.z*bfhi(kr[pp][2].x) + wq.w*bfhi(kr[pp][3].x);
            float g2 = wq.x*bflo(kr[pp][0].y) + wq.y*bflo(kr[pp][1].y)
                     + wq.z*bflo(kr[pp][2].y) + wq.w*bflo(kr[pp][3].y);
            float g3 = wq.x*bfhi(kr[pp][0].y) + wq.y*bfhi(kr[pp][1].y)
                     + wq.z*bfhi(kr[pp][2].y) + wq.w*bfhi(kr[pp][3].y);
            pk[pp].x = packbf2(g0, g1);
            pk[pp].y = packbf2(g2, g3);
        }

        __syncthreads();                  // previous tap's A-frag reads complete
#pragma unroll
        for (int pp = 0; pp < 8; ++pp) {
            const int P   = s_pb + pp;                     // pixel & 15
            const int row = (P ^ s_xr) | (s_q2 << 4);      // swizzled frag row
            *(uint2*)&Abuf[s_cc][s_mi][row][s_j0] = pk[pp];
        }
        __syncthreads();                  // tap's A tile visible

        // ---- MFMA: 8 K-steps of 32 channels, JIT B-frags (v1-proven) ----
        __builtin_amdgcn_s_setprio(1);
#pragma unroll
        for (int cc = 0; cc < 8; ++cc) {
            const int KC = tap * 8 + cc;
            const int rr = r_row ^ cc;
            uint4 braw[2];
#pragma unroll
            for (int nj = 0; nj < 2; ++nj)
                braw[nj] = wKf4[(size_t)((wv * 2 + nj) * 72 + KC) * 64 + lane];
            bf16x8 a[4];
#pragma unroll
            for (int mi = 0; mi < 4; ++mi)
                a[mi] = *(const bf16x8*)&Abuf[cc][mi][rr][0];
#pragma unroll
            for (int nj = 0; nj < 2; ++nj) {
                bf16x8 bb = __builtin_bit_cast(bf16x8, braw[nj]);
#pragma unroll
                for (int mi = 0; mi < 4; ++mi)
                    acc[mi][nj] = __builtin_amdgcn_mfma_f32_16x16x32_bf16(
                        a[mi], bb, acc[mi][nj], 0, 0, 0);
            }
        }
        __builtin_amdgcn_s_setprio(0);
    }

    // ---- epilogue: conv bias + BN + ReLU, nontemporal float4 stores ----
#pragma unroll
    for (int nj = 0; nj < 2; ++nj) {
        const int o = wv * 32 + nj * 16 + (lane & 15);
        const float inv = gamma[o] * rsqrtf(rvar[o] + BN_EPS);
        const float sh  = beta[o] + (bias[o] - rmean[o]) * inv;
        float* ob = out + ((size_t)(b * O_ + o)) * HW_ + h * W_;
#pragma unroll
        for (int mi = 0; mi < 4; ++mi) {
            f32x4 v = acc[mi][nj];
            f32x4 r;
            r[0] = fmaxf(v[0] * inv + sh, 0.f);
            r[1] = fmaxf(v[1] * inv + sh, 0.f);
            r[2] = fmaxf(v[2] * inv + sh, 0.f);
            r[3] = fmaxf(v[3] * inv + sh, 0.f);
            __builtin_nontemporal_store(r, (f32x4*)&ob[mi * 16 + (lane >> 4) * 4]);
        }
    }
}

extern "C" void kernel_launch(void* const* d_in, const int* in_sizes, int n_in,
                              void* d_out, int out_size, void* d_ws, size_t ws_size,
                              hipStream_t stream) {
    const float* x     = (const float*)d_in[0];
    const float* w_off = (const float*)d_in[1];
    const float* b_off = (const float*)d_in[2];
    const float* w     = (const float*)d_in[3];
    const float* bias  = (const float*)d_in[4];
    const float* gamma = (const float*)d_in[5];
    const float* beta  = (const float*)d_in[6];
    const float* rmean = (const float*)d_in[7];
    const float* rvar  = (const float*)d_in[8];
    float* out = (float*)d_out;

    unsigned short* xT  = (unsigned short*)d_ws;              // 8388608 bf16 (16 MB)
    unsigned short* wKf = xT + 8388608;                       // 589824 bf16
    unsigned short* wof = wKf + 589824;                       // 73728 bf16

    prep_kernel<<<656, 256, 0, stream>>>(x, w, w_off, xT, wKf, wof);
    dcn_fused_kernel<<<512, 512, 0, stream>>>(
        xT, wKf, wof, b_off, bias, gamma, beta, rmean, rvar, out);
}

// Round 10
// 177.241 us; speedup vs baseline: 1.1241x; 1.0120x over previous
//
#include <hip/hip_runtime.h>
#include <math.h>

#define B_   8
#define C_   256
#define H_   64
#define W_   64
#define O_   256
#define KK_  9
#define CK_  2304      // C_*KK_
#define HW_  4096      // H_*W_
#define BN_EPS 1e-5f

typedef __bf16 bf16x8 __attribute__((ext_vector_type(8)));
typedef float  f32x4  __attribute__((ext_vector_type(4)));
typedef float  f32x2  __attribute__((ext_vector_type(2)));

static __device__ __forceinline__ unsigned short f2bf(float f) {   // RNE (weights)
    unsigned int u = __float_as_uint(f);
    unsigned int r = (u + 0x7fffu + ((u >> 16) & 1u)) >> 16;
    return (unsigned short)r;
}
// pack two f32 -> bf16x2 with round-half-up (2 adds + 1 v_perm)
static __device__ __forceinline__ unsigned int packbf2(float lo, float hi) {
    unsigned int ul = __float_as_uint(lo) + 0x8000u;
    unsigned int uh = __float_as_uint(hi) + 0x8000u;
    return __builtin_amdgcn_perm(uh, ul, 0x07060302u);
}
static __device__ __forceinline__ float bflo(unsigned int u) {
    return __uint_as_float(u << 16);
}
static __device__ __forceinline__ float bfhi(unsigned int u) {
    return __uint_as_float(u & 0xffff0000u);
}
// unpack 2 packed bf16 -> f32x2 {lo, hi} (2 VALU; feeds v_pk_fma_f32)
static __device__ __forceinline__ f32x2 bf2x(unsigned int u) {
    f32x2 r;
    r[0] = __uint_as_float(u << 16);
    r[1] = __uint_as_float(u & 0xffff0000u);
    return r;
}

// ---- kernel 0: prep. 656 blocks x 256 thr. (R7 version, XCD-matched swizzle)
__global__ __launch_bounds__(256) void prep_kernel(
    const float* __restrict__ x, const float* __restrict__ w,
    const float* __restrict__ w_off,
    unsigned short* __restrict__ xT, unsigned short* __restrict__ wKf,
    unsigned short* __restrict__ wof)
{
    __shared__ float tile[64][65];     // transpose staging
    __shared__ float wbuf[4608];       // weight staging (16 o x 288)

    const int blk = blockIdx.x;
    const int tid = threadIdx.x, lane = tid & 63, tg = tid >> 6;

    if (blk < 512) {
        // XCD-contiguous h-chunks: XCD x gets h in [8x, 8x+8), all b.
        const int L = (blk & 7) * 64 + (blk >> 3);
        const int b = L & 7, h = L >> 3;
        const int hwb = h * W_;
#pragma unroll
        for (int ct = 0; ct < 4; ++ct) {
            const int c0 = ct * 64;
#pragma unroll
            for (int r = 0; r < 16; ++r) {
                int c_l = tg + r * 4;
                tile[c_l][lane] = x[((size_t)(b * C_ + c0 + c_l)) * HW_ + hwb + lane];
            }
            __syncthreads();
#pragma unroll
            for (int it = 0; it < 4; ++it) {
                const int hw_l = tg * 16 + it * 4 + (lane >> 4);
                const int c_l4 = (lane & 15) * 4;
                float v0 = tile[c_l4 + 0][hw_l];
                float v1 = tile[c_l4 + 1][hw_l];
                float v2 = tile[c_l4 + 2][hw_l];
                float v3 = tile[c_l4 + 3][hw_l];
                uint2 pk;
                pk.x = packbf2(v0, v1);
                pk.y = packbf2(v2, v3);
                *(uint2*)&xT[((size_t)(b * HW_ + hwb + hw_l)) * C_ + c0 + c_l4] = pk;
            }
            __syncthreads();
        }
    } else if (blk < 640) {
        const int t2 = blk - 512;
        const int NT = t2 >> 3, cb = t2 & 7;
#pragma unroll
        for (int i = 0; i < 18; ++i) {
            int j = i * 256 + tid;
            int o_l = j / 288, rest = j - o_l * 288;
            wbuf[o_l * 288 + rest] = w[(size_t)(NT * 16 + o_l) * CK_ + cb * 288 + rest];
        }
        __syncthreads();
#pragma unroll
        for (int i = 0; i < 18; ++i) {
            int d = i * 256 + tid;
            int tap = d >> 9, r5 = d & 511;
            int ln = r5 >> 3, e = r5 & 7;
            int n16 = ln & 15, q = ln >> 4;
            float val = wbuf[n16 * 288 + (q * 8 + e) * 9 + tap];
            wKf[((size_t)(NT * 72 + tap * 8 + cb) * 64 + ln) * 8 + e] = f2bf(val);
        }
    } else {
        const int t2 = blk - 640;
        const int NT = t2 >> 3, cb = t2 & 7;
#pragma unroll
        for (int i = 0; i < 18; ++i) {
            int j = i * 256 + tid;
            int o_l = j / 288, rest = j - o_l * 288;
            int o = NT * 16 + o_l;
            wbuf[o_l * 288 + rest] =
                (o < 27) ? w_off[(size_t)o * CK_ + cb * 288 + rest] : 0.f;
        }
        __syncthreads();
#pragma unroll
        for (int i = 0; i < 18; ++i) {
            int d = i * 256 + tid;
            int tap = d >> 9, r5 = d & 511;
            int ln = r5 >> 3, e = r5 & 7;
            int n16 = ln & 15, q = ln >> 4;
            float val = wbuf[n16 * 288 + (q * 8 + e) * 9 + tap];
            wof[((size_t)(NT * 72 + tap * 8 + cb) * 64 + ln) * 8 + e] = f2bf(val);
        }
    }
}

// ---- kernel 1: fused offset-conv (MFMA) + sample + MFMA GEMM + BN + ReLU
// 512 blocks / 512 thr / 8 waves.
// v10 = v7 (best, 86.5us: XCD swizzle + B-reg pipeline + setprio + nt stores)
//       + PACKED-F32 wsum: weighted 4-corner sum expressed in f32x2 so the
//       compiler emits v_pk_fma_f32 (8 pk-FMA instead of 16 scalar FMA per
//       pixel). Probes the sum-of-pipes model: VALU is ~20us of the ~93us
//       pipe sum; a 1/3 cut in sampling VALU should show directly if the
//       model holds.
__global__ __launch_bounds__(512, 4) void dcn_fused_kernel(
    const unsigned short* __restrict__ xT, const unsigned short* __restrict__ wKf,
    const unsigned short* __restrict__ wof, const float* __restrict__ b_off,
    const float* __restrict__ bias, const float* __restrict__ gamma,
    const float* __restrict__ beta, const float* __restrict__ rmean,
    const float* __restrict__ rvar, float* __restrict__ out)
{
    // region 0 (0..34847):      rowbuf [66][264] bf16 (phase A), then
    //                           wgtv[576] float4 (0..9215) + idxv[576] int4 (9216..18431)
    // region 1 (34848..41759):  omb [27][64] f32
    // region 2 (41760..74527):  Abuf [8][4][64][8] bf16
    __shared__ __align__(16) unsigned char smem[74528];
    unsigned short* rowbuf = (unsigned short*)smem;
    float4*         wgtv   = (float4*)smem;
    int4*           idxv   = (int4*)(smem + 9216);
    typedef float OmbT[27][64];
    OmbT& omb = *(OmbT*)(smem + 34848);
    typedef unsigned short AbufT[8][4][64][8];
    AbufT& Abuf = *(AbufT*)(smem + 41760);

    // XCD-contiguous h-chunks (bijective: 512 = 8 XCD x 64)
    const int pblk = blockIdx.x;
    const int L = (pblk & 7) * 64 + (pblk >> 3);
    const int b = L & 7, h = L >> 3;
    const int tid = threadIdx.x, lane = tid & 63, wv = tid >> 6;
    const int m16 = lane & 15, q = lane >> 4;

    // ================= Phase A: offset conv =================
    if (tid < 33) {                                  // zero halo px=-1 (row 0)
        *(uint4*)&rowbuf[tid * 8] = make_uint4(0u, 0u, 0u, 0u);
    } else if (tid >= 256 && tid < 289) {            // zero halo px=64 (row 65)
        *(uint4*)&rowbuf[65 * 264 + (tid - 256) * 8] = make_uint4(0u, 0u, 0u, 0u);
    }

    const int mi_a = wv & 3, nj_a = wv >> 2;
    f32x4 oacc = {0.f, 0.f, 0.f, 0.f};
    const uint4* wof4 = (const uint4*)wof;

    for (int r = 0; r < 3; ++r) {
        const int hh = h - 1 + r;
        const bool vr = (hh >= 0) && (hh < H_);      // block-uniform
        __syncthreads();                             // prior r reads done / halos visible
        if (vr) {
            const uint4* src = (const uint4*)&xT[((size_t)(b * HW_ + hh * W_)) * C_];
#pragma unroll
            for (int i = 0; i < 4; ++i) {
                const int idx8 = i * 512 + tid;      // 2048 chunks of 8 ch (16 B)
                uint4 v = src[idx8];
                const int px = idx8 >> 5, c8 = (idx8 & 31) * 8;
                *(uint4*)&rowbuf[(px + 1) * 264 + c8] = v;
            }
        }
        __syncthreads();
        if (vr) {
#pragma unroll
            for (int s = 0; s < 3; ++s) {
                const unsigned short* arow = &rowbuf[(mi_a * 16 + m16 + s) * 264 + q * 8];
#pragma unroll
                for (int cc = 0; cc < 8; ++cc) {
                    bf16x8 a = *(const bf16x8*)&arow[cc * 32];
                    uint4 braw = wof4[(size_t)(nj_a * 72 + (r * 3 + s) * 8 + cc) * 64 + lane];
                    oacc = __builtin_amdgcn_mfma_f32_16x16x32_bf16(
                        a, __builtin_bit_cast(bf16x8, braw), oacc, 0, 0, 0);
                }
            }
        }
    }
    // phase-A epilogue: bias + sigmoid(mod) -> omb[t][px]
    {
        const int t = nj_a * 16 + m16;
        if (t < 27) {
            const float bo = b_off[t];
            float s0 = oacc[0] + bo, s1 = oacc[1] + bo,
                  s2 = oacc[2] + bo, s3 = oacc[3] + bo;
            if (t >= 18) {
                s0 = 1.f / (1.f + expf(-s0));
                s1 = 1.f / (1.f + expf(-s1));
                s2 = 1.f / (1.f + expf(-s2));
                s3 = 1.f / (1.f + expf(-s3));
            }
            float4 rr; rr.x = s0; rr.y = s1; rr.z = s2; rr.w = s3;
            *(float4*)&omb[t][mi_a * 16 + q * 4] = rr;
        }
    }
    __syncthreads();                      // omb visible; rowbuf dead

    // ---- per-(pixel,tap) tables (overwrite rowbuf region) ----
    for (int i = tid; i < 576; i += 512) {
        int p = i / 9, t = i - p * 9;
        float dy = omb[t][p];
        float dx = omb[t + 9][p];
        float md = omb[t + 18][p];
        float py = (float)(h - 1 + t / 3) + dy;
        float px = (float)(p - 1 + t % 3) + dx;
        float y0f = floorf(py), x0f = floorf(px);
        int   y0 = (int)y0f,    x0 = (int)x0f;
        float fy = py - y0f,    fx = px - x0f;
        int y0c = min(max(y0,     0), H_ - 1), y1c = min(max(y0 + 1, 0), H_ - 1);
        int x0c = min(max(x0,     0), W_ - 1), x1c = min(max(x0 + 1, 0), W_ - 1);
        float vy0 = (y0     >= 0 && y0     < H_) ? 1.f : 0.f;
        float vy1 = (y0 + 1 >= 0 && y0 + 1 < H_) ? 1.f : 0.f;
        float vx0 = (x0     >= 0 && x0     < W_) ? 1.f : 0.f;
        float vx1 = (x0 + 1 >= 0 && x0 + 1 < W_) ? 1.f : 0.f;
        wgtv[i] = make_float4((1.f - fy) * (1.f - fx) * vy0 * vx0 * md,
                              (1.f - fy) * fx         * vy0 * vx1 * md,
                              fy         * (1.f - fx) * vy1 * vx0 * md,
                              fy         * fx         * vy1 * vx1 * md);
        const int rowb = (b * HW_) * (C_ * 2);       // byte offset of batch b in xT
        idxv[i] = make_int4(rowb + (y0c * W_ + x0c) * (C_ * 2),
                            rowb + (y0c * W_ + x1c) * (C_ * 2),
                            rowb + (y1c * W_ + x0c) * (C_ * 2),
                            rowb + (y1c * W_ + x1c) * (C_ * 2));
    }
    __syncthreads();

    // ================= Phase B: sample + GEMM =================
    f32x4 acc[4][2];
#pragma unroll
    for (int mi = 0; mi < 4; ++mi)
#pragma unroll
        for (int nj = 0; nj < 2; ++nj)
#pragma unroll
            for (int r = 0; r < 4; ++r) acc[mi][nj][r] = 0.f;

    const uint4* wKf4 = (const uint4*)wKf;
    const char*  xTb  = (const char*)xT;

    // sampling write-dest precompute (lane covers channels 4*lane .. 4*lane+3)
    const int s_cc = lane >> 3;                   // 32-ch chunk
    const int s_q2 = (lane >> 1) & 3;             // k-quad within chunk
    const int s_j0 = (lane & 1) * 4;              // element offset within frag row
    const int s_xr = (s_q2 << 1) ^ s_cc;          // XOR swizzle for bank spread
    const int s_mi = wv >> 1;                     // m-tile this wave's pixels fall in
    const int s_pb = (wv & 1) * 8;                // pixel base within m-tile
    const int loff = lane * 8;                    // byte offset within 512-B pixel row

    const int r_row = lane ^ ((lane >> 4) << 1);  // MFMA-side read row (pre-XOR by cc)

    // B-pipeline registers: bA/bB each hold one cc-pair batch {2cc x 2nj}
    uint4 bA[4], bB[4];
    auto loadB = [&](uint4* dst, int t_, int p_) {
#pragma unroll
        for (int c2 = 0; c2 < 2; ++c2)
#pragma unroll
            for (int nj = 0; nj < 2; ++nj)
                dst[c2 * 2 + nj] =
                    wKf4[(size_t)((wv * 2 + nj) * 72 + t_ * 8 + p_ * 2 + c2) * 64 + lane];
    };
    auto mfmaPair = [&](int p_, const uint4* Bf) {
#pragma unroll
        for (int c2 = 0; c2 < 2; ++c2) {
            const int cc = p_ * 2 + c2;
            const int rr = r_row ^ cc;
            bf16x8 a[4];
#pragma unroll
            for (int mi = 0; mi < 4; ++mi)
                a[mi] = *(const bf16x8*)&Abuf[cc][mi][rr][0];
#pragma unroll
            for (int nj = 0; nj < 2; ++nj) {
                bf16x8 bb = __builtin_bit_cast(bf16x8, Bf[c2 * 2 + nj]);
#pragma unroll
                for (int mi = 0; mi < 4; ++mi)
                    acc[mi][nj] = __builtin_amdgcn_mfma_f32_16x16x32_bf16(
                        a[mi], bb, acc[mi][nj], 0, 0, 0);
            }
        }
    };

    // preload tap0 cc{0,1}: latency hidden under the first sampling segment
    loadB(bA, 0, 0);

#pragma unroll 1
    for (int tap = 0; tap < 9; ++tap) {
        // ---- sample 8 pixels: coalesced 512-B corner loads, pk-f32 wsum ----
        uint2 pk[8];
#pragma unroll
        for (int pp = 0; pp < 8; ++pp) {
            const int p = wv * 8 + pp;
            const int4   iq = idxv[p * 9 + tap];
            const float4 wq = wgtv[p * 9 + tap];
            const uint2 k0 = *(const uint2*)(xTb + iq.x + loff);
            const uint2 k1 = *(const uint2*)(xTb + iq.y + loff);
            const uint2 k2 = *(const uint2*)(xTb + iq.z + loff);
            const uint2 k3 = *(const uint2*)(xTb + iq.w + loff);
            const f32x2 wx = {wq.x, wq.x}, wy = {wq.y, wq.y},
                        wz = {wq.z, wq.z}, ww = {wq.w, wq.w};
            f32x2 g01 = wx * bf2x(k0.x) + wy * bf2x(k1.x)
                      + wz * bf2x(k2.x) + ww * bf2x(k3.x);
            f32x2 g23 = wx * bf2x(k0.y) + wy * bf2x(k1.y)
                      + wz * bf2x(k2.y) + ww * bf2x(k3.y);
            pk[pp].x = packbf2(g01[0], g01[1]);
            pk[pp].y = packbf2(g23[0], g23[1]);
        }

        __syncthreads();                  // previous tap's A-frag reads complete
                                          // (also drains vmcnt -> bA is in regs)
#pragma unroll
        for (int pp = 0; pp < 8; ++pp) {
            const int P   = s_pb + pp;                     // pixel & 15
            const int row = (P ^ s_xr) | (s_q2 << 4);      // swizzled frag row
            *(uint2*)&Abuf[s_cc][s_mi][row][s_j0] = pk[pp];
        }
        __syncthreads();                  // tap's A tile visible

        // ---- MFMA: 8 K-steps, B-frags pipelined one cc-pair ahead ----
        __builtin_amdgcn_s_setprio(1);
        loadB(bB, tap, 1);                // cc2,3 in flight under MFMA(cc0,1)
        mfmaPair(0, bA);
        loadB(bA, tap, 2);                // cc4,5
        mfmaPair(1, bB);
        loadB(bB, tap, 3);                // cc6,7
        mfmaPair(2, bA);
        if (tap < 8) loadB(bA, tap + 1, 0);   // next tap cc0,1 — drained by the
                                              // next iteration's barriers for free
        mfmaPair(3, bB);
        __builtin_amdgcn_s_setprio(0);
    }

    // ---- epilogue: conv bias + BN + ReLU, nontemporal float4 stores ----
#pragma unroll
    for (int nj = 0; nj < 2; ++nj) {
        const int o = wv * 32 + nj * 16 + (lane & 15);
        const float inv = gamma[o] * rsqrtf(rvar[o] + BN_EPS);
        const float sh  = beta[o] + (bias[o] - rmean[o]) * inv;
        float* ob = out + ((size_t)(b * O_ + o)) * HW_ + h * W_;
#pragma unroll
        for (int mi = 0; mi < 4; ++mi) {
            f32x4 v = acc[mi][nj];
            f32x4 r;
            r[0] = fmaxf(v[0] * inv + sh, 0.f);
            r[1] = fmaxf(v[1] * inv + sh, 0.f);
            r[2] = fmaxf(v[2] * inv + sh, 0.f);
            r[3] = fmaxf(v[3] * inv + sh, 0.f);
            __builtin_nontemporal_store(r, (f32x4*)&ob[mi * 16 + (lane >> 4) * 4]);
        }
    }
}

extern "C" void kernel_launch(void* const* d_in, const int* in_sizes, int n_in,
                              void* d_out, int out_size, void* d_ws, size_t ws_size,
                              hipStream_t stream) {
    const float* x     = (const float*)d_in[0];
    const float* w_off = (const float*)d_in[1];
    const float* b_off = (const float*)d_in[2];
    const float* w     = (const float*)d_in[3];
    const float* bias  = (const float*)d_in[4];
    const float* gamma = (const float*)d_in[5];
    const float* beta  = (const float*)d_in[6];
    const float* rmean = (const float*)d_in[7];
    const float* rvar  = (const float*)d_in[8];
    float* out = (float*)d_out;

    unsigned short* xT  = (unsigned short*)d_ws;              // 8388608 bf16 (16 MB)
    unsigned short* wKf = xT + 8388608;                       // 589824 bf16
    unsigned short* wof = wKf + 589824;                       // 73728 bf16

    prep_kernel<<<656, 256, 0, stream>>>(x, w, w_off, xT, wKf, wof);
    dcn_fused_kernel<<<512, 512, 0, stream>>>(
        xT, wKf, wof, b_off, bias, gamma, beta, rmean, rvar, out);
}

// Round 11
// 170.169 us; speedup vs baseline: 1.1708x; 1.0416x over previous
//
#include <hip/hip_runtime.h>
#include <math.h>

#define B_   8
#define C_   256
#define H_   64
#define W_   64
#define O_   256
#define KK_  9
#define CK_  2304      // C_*KK_
#define HW_  4096      // H_*W_
#define BN_EPS 1e-5f

typedef __bf16 bf16x8 __attribute__((ext_vector_type(8)));
typedef float  f32x4  __attribute__((ext_vector_type(4)));
typedef float  f32x2  __attribute__((ext_vector_type(2)));

static __device__ __forceinline__ unsigned short f2bf(float f) {   // RNE (weights)
    unsigned int u = __float_as_uint(f);
    unsigned int r = (u + 0x7fffu + ((u >> 16) & 1u)) >> 16;
    return (unsigned short)r;
}
// pack two f32 -> bf16x2 with round-half-up (2 adds + 1 v_perm)
static __device__ __forceinline__ unsigned int packbf2(float lo, float hi) {
    unsigned int ul = __float_as_uint(lo) + 0x8000u;
    unsigned int uh = __float_as_uint(hi) + 0x8000u;
    return __builtin_amdgcn_perm(uh, ul, 0x07060302u);
}
// unpack 2 packed bf16 -> f32x2 {lo, hi} (2 VALU; feeds v_pk_fma_f32)
static __device__ __forceinline__ f32x2 bf2x(unsigned int u) {
    f32x2 r;
    r[0] = __uint_as_float(u << 16);
    r[1] = __uint_as_float(u & 0xffff0000u);
    return r;
}

// ---- kernel 0: prep. 656 blocks x 256 thr. (R7 version, XCD-matched swizzle)
__global__ __launch_bounds__(256) void prep_kernel(
    const float* __restrict__ x, const float* __restrict__ w,
    const float* __restrict__ w_off,
    unsigned short* __restrict__ xT, unsigned short* __restrict__ wKf,
    unsigned short* __restrict__ wof)
{
    __shared__ float tile[64][65];     // transpose staging
    __shared__ float wbuf[4608];       // weight staging (16 o x 288)

    const int blk = blockIdx.x;
    const int tid = threadIdx.x, lane = tid & 63, tg = tid >> 6;

    if (blk < 512) {
        // XCD-contiguous h-chunks: XCD x gets h in [8x, 8x+8), all b.
        const int L = (blk & 7) * 64 + (blk >> 3);
        const int b = L & 7, h = L >> 3;
        const int hwb = h * W_;
#pragma unroll
        for (int ct = 0; ct < 4; ++ct) {
            const int c0 = ct * 64;
#pragma unroll
            for (int r = 0; r < 16; ++r) {
                int c_l = tg + r * 4;
                tile[c_l][lane] = x[((size_t)(b * C_ + c0 + c_l)) * HW_ + hwb + lane];
            }
            __syncthreads();
#pragma unroll
            for (int it = 0; it < 4; ++it) {
                const int hw_l = tg * 16 + it * 4 + (lane >> 4);
                const int c_l4 = (lane & 15) * 4;
                float v0 = tile[c_l4 + 0][hw_l];
                float v1 = tile[c_l4 + 1][hw_l];
                float v2 = tile[c_l4 + 2][hw_l];
                float v3 = tile[c_l4 + 3][hw_l];
                uint2 pk;
                pk.x = packbf2(v0, v1);
                pk.y = packbf2(v2, v3);
                *(uint2*)&xT[((size_t)(b * HW_ + hwb + hw_l)) * C_ + c0 + c_l4] = pk;
            }
            __syncthreads();
        }
    } else if (blk < 640) {
        const int t2 = blk - 512;
        const int NT = t2 >> 3, cb = t2 & 7;
#pragma unroll
        for (int i = 0; i < 18; ++i) {
            int j = i * 256 + tid;
            int o_l = j / 288, rest = j - o_l * 288;
            wbuf[o_l * 288 + rest] = w[(size_t)(NT * 16 + o_l) * CK_ + cb * 288 + rest];
        }
        __syncthreads();
#pragma unroll
        for (int i = 0; i < 18; ++i) {
            int d = i * 256 + tid;
            int tap = d >> 9, r5 = d & 511;
            int ln = r5 >> 3, e = r5 & 7;
            int n16 = ln & 15, q = ln >> 4;
            float val = wbuf[n16 * 288 + (q * 8 + e) * 9 + tap];
            wKf[((size_t)(NT * 72 + tap * 8 + cb) * 64 + ln) * 8 + e] = f2bf(val);
        }
    } else {
        const int t2 = blk - 640;
        const int NT = t2 >> 3, cb = t2 & 7;
#pragma unroll
        for (int i = 0; i < 18; ++i) {
            int j = i * 256 + tid;
            int o_l = j / 288, rest = j - o_l * 288;
            int o = NT * 16 + o_l;
            wbuf[o_l * 288 + rest] =
                (o < 27) ? w_off[(size_t)o * CK_ + cb * 288 + rest] : 0.f;
        }
        __syncthreads();
#pragma unroll
        for (int i = 0; i < 18; ++i) {
            int d = i * 256 + tid;
            int tap = d >> 9, r5 = d & 511;
            int ln = r5 >> 3, e = r5 & 7;
            int n16 = ln & 15, q = ln >> 4;
            float val = wbuf[n16 * 288 + (q * 8 + e) * 9 + tap];
            wof[((size_t)(NT * 72 + tap * 8 + cb) * 64 + ln) * 8 + e] = f2bf(val);
        }
    }
}

// ---- kernel 1: fused offset-conv (MFMA) + sample + MFMA GEMM + BN + ReLU
// 512 blocks / 512 thr / 8 waves.
// v11 = v7 + 2-PX-PER-INSTR sampling (identical bytes, thinner stream):
//   half-wave per pixel, 16 B/lane. Table ds_reads 16->8 (divergent reads
//   serve both halves), gather VMEM issues 32->16, Abuf writes 8xb64->4xb128.
//   Writer mapping is the exact inverse of the UNCHANGED MFMA reader.
//   s_setprio removed (wraps VMEM issue; hurts GEMM-shaped loops).
__global__ __launch_bounds__(512, 4) void dcn_fused_kernel(
    const unsigned short* __restrict__ xT, const unsigned short* __restrict__ wKf,
    const unsigned short* __restrict__ wof, const float* __restrict__ b_off,
    const float* __restrict__ bias, const float* __restrict__ gamma,
    const float* __restrict__ beta, const float* __restrict__ rmean,
    const float* __restrict__ rvar, float* __restrict__ out)
{
    // region 0 (0..34847):      rowbuf [66][264] bf16 (phase A), then
    //                           wgtv[576] float4 (0..9215) + idxv[576] int4 (9216..18431)
    // region 1 (34848..41759):  omb [27][64] f32
    // region 2 (41760..74527):  Abuf [8][4][64][8] bf16
    __shared__ __align__(16) unsigned char smem[74528];
    unsigned short* rowbuf = (unsigned short*)smem;
    float4*         wgtv   = (float4*)smem;
    int4*           idxv   = (int4*)(smem + 9216);
    typedef float OmbT[27][64];
    OmbT& omb = *(OmbT*)(smem + 34848);
    typedef unsigned short AbufT[8][4][64][8];
    AbufT& Abuf = *(AbufT*)(smem + 41760);

    // XCD-contiguous h-chunks (bijective: 512 = 8 XCD x 64)
    const int pblk = blockIdx.x;
    const int L = (pblk & 7) * 64 + (pblk >> 3);
    const int b = L & 7, h = L >> 3;
    const int tid = threadIdx.x, lane = tid & 63, wv = tid >> 6;
    const int m16 = lane & 15, q = lane >> 4;

    // ================= Phase A: offset conv =================
    if (tid < 33) {                                  // zero halo px=-1 (row 0)
        *(uint4*)&rowbuf[tid * 8] = make_uint4(0u, 0u, 0u, 0u);
    } else if (tid >= 256 && tid < 289) {            // zero halo px=64 (row 65)
        *(uint4*)&rowbuf[65 * 264 + (tid - 256) * 8] = make_uint4(0u, 0u, 0u, 0u);
    }

    const int mi_a = wv & 3, nj_a = wv >> 2;
    f32x4 oacc = {0.f, 0.f, 0.f, 0.f};
    const uint4* wof4 = (const uint4*)wof;

    for (int r = 0; r < 3; ++r) {
        const int hh = h - 1 + r;
        const bool vr = (hh >= 0) && (hh < H_);      // block-uniform
        __syncthreads();                             // prior r reads done / halos visible
        if (vr) {
            const uint4* src = (const uint4*)&xT[((size_t)(b * HW_ + hh * W_)) * C_];
#pragma unroll
            for (int i = 0; i < 4; ++i) {
                const int idx8 = i * 512 + tid;      // 2048 chunks of 8 ch (16 B)
                uint4 v = src[idx8];
                const int px = idx8 >> 5, c8 = (idx8 & 31) * 8;
                *(uint4*)&rowbuf[(px + 1) * 264 + c8] = v;
            }
        }
        __syncthreads();
        if (vr) {
#pragma unroll
            for (int s = 0; s < 3; ++s) {
                const unsigned short* arow = &rowbuf[(mi_a * 16 + m16 + s) * 264 + q * 8];
#pragma unroll
                for (int cc = 0; cc < 8; ++cc) {
                    bf16x8 a = *(const bf16x8*)&arow[cc * 32];
                    uint4 braw = wof4[(size_t)(nj_a * 72 + (r * 3 + s) * 8 + cc) * 64 + lane];
                    oacc = __builtin_amdgcn_mfma_f32_16x16x32_bf16(
                        a, __builtin_bit_cast(bf16x8, braw), oacc, 0, 0, 0);
                }
            }
        }
    }
    // phase-A epilogue: bias + sigmoid(mod) -> omb[t][px]
    {
        const int t = nj_a * 16 + m16;
        if (t < 27) {
            const float bo = b_off[t];
            float s0 = oacc[0] + bo, s1 = oacc[1] + bo,
                  s2 = oacc[2] + bo, s3 = oacc[3] + bo;
            if (t >= 18) {
                s0 = 1.f / (1.f + expf(-s0));
                s1 = 1.f / (1.f + expf(-s1));
                s2 = 1.f / (1.f + expf(-s2));
                s3 = 1.f / (1.f + expf(-s3));
            }
            float4 rr; rr.x = s0; rr.y = s1; rr.z = s2; rr.w = s3;
            *(float4*)&omb[t][mi_a * 16 + q * 4] = rr;
        }
    }
    __syncthreads();                      // omb visible; rowbuf dead

    // ---- per-(pixel,tap) tables (overwrite rowbuf region) ----
    for (int i = tid; i < 576; i += 512) {
        int p = i / 9, t = i - p * 9;
        float dy = omb[t][p];
        float dx = omb[t + 9][p];
        float md = omb[t + 18][p];
        float py = (float)(h - 1 + t / 3) + dy;
        float px = (float)(p - 1 + t % 3) + dx;
        float y0f = floorf(py), x0f = floorf(px);
        int   y0 = (int)y0f,    x0 = (int)x0f;
        float fy = py - y0f,    fx = px - x0f;
        int y0c = min(max(y0,     0), H_ - 1), y1c = min(max(y0 + 1, 0), H_ - 1);
        int x0c = min(max(x0,     0), W_ - 1), x1c = min(max(x0 + 1, 0), W_ - 1);
        float vy0 = (y0     >= 0 && y0     < H_) ? 1.f : 0.f;
        float vy1 = (y0 + 1 >= 0 && y0 + 1 < H_) ? 1.f : 0.f;
        float vx0 = (x0     >= 0 && x0     < W_) ? 1.f : 0.f;
        float vx1 = (x0 + 1 >= 0 && x0 + 1 < W_) ? 1.f : 0.f;
        wgtv[i] = make_float4((1.f - fy) * (1.f - fx) * vy0 * vx0 * md,
                              (1.f - fy) * fx         * vy0 * vx1 * md,
                              fy         * (1.f - fx) * vy1 * vx0 * md,
                              fy         * fx         * vy1 * vx1 * md);
        const int rowb = (b * HW_) * (C_ * 2);       // byte offset of batch b in xT
        idxv[i] = make_int4(rowb + (y0c * W_ + x0c) * (C_ * 2),
                            rowb + (y0c * W_ + x1c) * (C_ * 2),
                            rowb + (y1c * W_ + x0c) * (C_ * 2),
                            rowb + (y1c * W_ + x1c) * (C_ * 2));
    }
    __syncthreads();

    // ================= Phase B: sample + GEMM =================
    f32x4 acc[4][2];
#pragma unroll
    for (int mi = 0; mi < 4; ++mi)
#pragma unroll
        for (int nj = 0; nj < 2; ++nj)
#pragma unroll
            for (int r = 0; r < 4; ++r) acc[mi][nj][r] = 0.f;

    const uint4* wKf4 = (const uint4*)wKf;
    const char*  xTb  = (const char*)xT;

    // ---- 2-px-per-instr sampling decomposition ----
    const int half = lane >> 5;                   // which px of the pair
    const int c32  = lane & 31;                   // 8-ch chunk within pixel
    const int w_cc = c32 >> 2;                    // k-group (32 ch)
    const int w_q2 = c32 & 3;                     // k-quad within group
    const int s_mi = wv >> 1;                     // m-tile this wave's pixels fall in
    const int s_pb = (wv & 1) * 8;                // pixel base within m-tile
    const int goff = c32 * 16;                    // byte offset within 512-B pixel row

    const int r_row = lane ^ ((lane >> 4) << 1);  // MFMA-side read row (pre-XOR by cc)

    // B-pipeline registers: bA/bB each hold one cc-pair batch {2cc x 2nj}
    uint4 bA[4], bB[4];
    auto loadB = [&](uint4* dst, int t_, int p_) {
#pragma unroll
        for (int c2 = 0; c2 < 2; ++c2)
#pragma unroll
            for (int nj = 0; nj < 2; ++nj)
                dst[c2 * 2 + nj] =
                    wKf4[(size_t)((wv * 2 + nj) * 72 + t_ * 8 + p_ * 2 + c2) * 64 + lane];
    };
    auto mfmaPair = [&](int p_, const uint4* Bf) {
#pragma unroll
        for (int c2 = 0; c2 < 2; ++c2) {
            const int cc = p_ * 2 + c2;
            const int rr = r_row ^ cc;
            bf16x8 a[4];
#pragma unroll
            for (int mi = 0; mi < 4; ++mi)
                a[mi] = *(const bf16x8*)&Abuf[cc][mi][rr][0];
#pragma unroll
            for (int nj = 0; nj < 2; ++nj) {
                bf16x8 bb = __builtin_bit_cast(bf16x8, Bf[c2 * 2 + nj]);
#pragma unroll
                for (int mi = 0; mi < 4; ++mi)
                    acc[mi][nj] = __builtin_amdgcn_mfma_f32_16x16x32_bf16(
                        a[mi], bb, acc[mi][nj], 0, 0, 0);
            }
        }
    };

    // sample one tap: 4 px-pairs, half-wave per px, 8 ch (16 B) per lane
    auto sampleTap = [&](int tap, uint4* pk4) {
#pragma unroll
        for (int pr = 0; pr < 4; ++pr) {
            const int pl = wv * 8 + pr * 2 + half;          // lane's pixel
            const int4   iq = idxv[pl * 9 + tap];           // divergent ds_read
            const float4 wq = wgtv[pl * 9 + tap];
            const char* bse = xTb + goff;
            const uint4 k0 = *(const uint4*)(bse + iq.x);
            const uint4 k1 = *(const uint4*)(bse + iq.y);
            const uint4 k2 = *(const uint4*)(bse + iq.z);
            const uint4 k3 = *(const uint4*)(bse + iq.w);
            const f32x2 wx = {wq.x, wq.x}, wy = {wq.y, wq.y},
                        wz = {wq.z, wq.z}, ww = {wq.w, wq.w};
            f32x2 g0 = wx*bf2x(k0.x) + wy*bf2x(k1.x) + wz*bf2x(k2.x) + ww*bf2x(k3.x);
            f32x2 g1 = wx*bf2x(k0.y) + wy*bf2x(k1.y) + wz*bf2x(k2.y) + ww*bf2x(k3.y);
            f32x2 g2 = wx*bf2x(k0.z) + wy*bf2x(k1.z) + wz*bf2x(k2.z) + ww*bf2x(k3.z);
            f32x2 g3 = wx*bf2x(k0.w) + wy*bf2x(k1.w) + wz*bf2x(k2.w) + ww*bf2x(k3.w);
            pk4[pr].x = packbf2(g0[0], g0[1]);
            pk4[pr].y = packbf2(g1[0], g1[1]);
            pk4[pr].z = packbf2(g2[0], g2[1]);
            pk4[pr].w = packbf2(g3[0], g3[1]);
        }
    };
    // write 4 px-pairs into Abuf (one b128 per pair; inverse of MFMA reader)
    auto writeTap = [&](const uint4* pk4) {
#pragma unroll
        for (int pr = 0; pr < 4; ++pr) {
            const int Pt  = s_pb + pr * 2 + half;                // px & 15
            const int row = (Pt ^ ((w_q2 << 1) ^ w_cc)) | (w_q2 << 4);
            *(uint4*)&Abuf[w_cc][s_mi][row][0] = pk4[pr];
        }
    };

    // preload tap0 cc{0,1}: latency hidden under the first sampling segment
    loadB(bA, 0, 0);

#pragma unroll 1
    for (int tap = 0; tap < 9; ++tap) {
        uint4 pk4[4];
        sampleTap(tap, pk4);

        __syncthreads();                  // previous tap's A-frag reads complete
                                          // (also drains vmcnt -> bA in regs)
        writeTap(pk4);
        __syncthreads();                  // tap's A tile visible

        // ---- MFMA: 8 K-steps, B-frags pipelined one cc-pair ahead ----
        loadB(bB, tap, 1);                // cc2,3 in flight under MFMA(cc0,1)
        mfmaPair(0, bA);
        loadB(bA, tap, 2);                // cc4,5
        mfmaPair(1, bB);
        loadB(bB, tap, 3);                // cc6,7
        mfmaPair(2, bA);
        if (tap < 8) loadB(bA, tap + 1, 0);   // next tap cc0,1 — drained by the
                                              // next iteration's barriers for free
        mfmaPair(3, bB);
    }

    // ---- epilogue: conv bias + BN + ReLU, nontemporal float4 stores ----
#pragma unroll
    for (int nj = 0; nj < 2; ++nj) {
        const int o = wv * 32 + nj * 16 + (lane & 15);
        const float inv = gamma[o] * rsqrtf(rvar[o] + BN_EPS);
        const float sh  = beta[o] + (bias[o] - rmean[o]) * inv;
        float* ob = out + ((size_t)(b * O_ + o)) * HW_ + h * W_;
#pragma unroll
        for (int mi = 0; mi < 4; ++mi) {
            f32x4 v = acc[mi][nj];
            f32x4 r;
            r[0] = fmaxf(v[0] * inv + sh, 0.f);
            r[1] = fmaxf(v[1] * inv + sh, 0.f);
            r[2] = fmaxf(v[2] * inv + sh, 0.f);
            r[3] = fmaxf(v[3] * inv + sh, 0.f);
            __builtin_nontemporal_store(r, (f32x4*)&ob[mi * 16 + (lane >> 4) * 4]);
        }
    }
}

extern "C" void kernel_launch(void* const* d_in, const int* in_sizes, int n_in,
                              void* d_out, int out_size, void* d_ws, size_t ws_size,
                              hipStream_t stream) {
    const float* x     = (const float*)d_in[0];
    const float* w_off = (const float*)d_in[1];
    const float* b_off = (const float*)d_in[2];
    const float* w     = (const float*)d_in[3];
    const float* bias  = (const float*)d_in[4];
    const float* gamma = (const float*)d_in[5];
    const float* beta  = (const float*)d_in[6];
    const float* rmean = (const float*)d_in[7];
    const float* rvar  = (const float*)d_in[8];
    float* out = (float*)d_out;

    unsigned short* xT  = (unsigned short*)d_ws;              // 8388608 bf16 (16 MB)
    unsigned short* wKf = xT + 8388608;                       // 589824 bf16
    unsigned short* wof = wKf + 589824;                       // 73728 bf16

    prep_kernel<<<656, 256, 0, stream>>>(x, w, w_off, xT, wKf, wof);
    dcn_fused_kernel<<<512, 512, 0, stream>>>(
        xT, wKf, wof, b_off, bias, gamma, beta, rmean, rvar, out);
}